// Round 1
// baseline (381.222 us; speedup 1.0000x reference)
//
#include <hip/hip_runtime.h>
#include <hip/hip_bf16.h>
#include <math.h>

#define BD 8        // batch
#define TD 1024     // T
#define CD 1024     // C
#define PD 100      // patterns
#define LAMBDA 0.1f
#define SIM_THR 0.5f

// -------- device-global scratch (written fully each call; deterministic) -----
__device__ float g_ctx_h[BD * CD];   // (B, C)
__device__ float g_trg_h[PD * CD];   // (P, C)
__device__ float g_logits[BD * PD];  // (B, P)
__device__ int   g_nnz;
__device__ int   g_idx[PD];
__device__ float g_w[PD];            // compacted weights, lambda folded in

// -------- K1: hidden = X @ W1part  (tiled over rows to reuse W1 columns) ----
// ROWS=8 (context, W1[:C]) or ROWS=10 (trigger chunk, W1[C:])
template <int ROWS, bool IS_CTX>
__global__ __launch_bounds__(256) void hidden_kernel(const float* __restrict__ context,
                                                     const float* __restrict__ triggers,
                                                     const float* __restrict__ W1) {
    const int c = blockIdx.x * 256 + threadIdx.x;          // output column
    const float* __restrict__ W1p = IS_CTX ? W1 : (W1 + (size_t)CD * CD);
    const float* __restrict__ src = IS_CTX ? context : (triggers + (size_t)blockIdx.y * 10 * CD);
    float*       __restrict__ dst = IS_CTX ? g_ctx_h : (g_trg_h + (size_t)blockIdx.y * 10 * CD);

    __shared__ float s_src[ROWS][64];
    float acc[ROWS];
#pragma unroll
    for (int i = 0; i < ROWS; ++i) acc[i] = 0.f;

    for (int kt = 0; kt < CD; kt += 64) {
        __syncthreads();
        for (int t = threadIdx.x; t < ROWS * 64; t += 256)
            s_src[t >> 6][t & 63] = src[(size_t)(t >> 6) * CD + kt + (t & 63)];
        __syncthreads();
#pragma unroll 4
        for (int kk = 0; kk < 64; ++kk) {
            const float wv = W1p[(size_t)(kt + kk) * CD + c];
#pragma unroll
            for (int i = 0; i < ROWS; ++i)
                acc[i] = fmaf(s_src[i][kk], wv, acc[i]);
        }
    }
#pragma unroll
    for (int i = 0; i < ROWS; ++i) dst[(size_t)i * CD + c] = acc[i];
}

// -------- K2: logits[b,p] = relu(ctx_h[b]+trg_h[p]+b1) . W2 + b2  -----------
__global__ __launch_bounds__(256) void logits_kernel(const float* __restrict__ b1,
                                                     const float* __restrict__ W2,
                                                     const float* __restrict__ b2) {
    const int wave = threadIdx.x >> 6;
    const int lane = threadIdx.x & 63;
    const int idx  = blockIdx.x * 4 + wave;   // 0..799
    const int b = idx / PD;
    const int p = idx % PD;

    float sum = 0.f;
    for (int c = lane; c < CD; c += 64) {
        float h = g_ctx_h[b * CD + c] + g_trg_h[p * CD + c] + b1[c];
        h = fmaxf(h, 0.f);
        sum = fmaf(h, W2[c], sum);
    }
#pragma unroll
    for (int off = 32; off > 0; off >>= 1) sum += __shfl_down(sum, off);
    if (lane == 0) g_logits[idx] = sum + b2[0];
}

// -------- K3: scores -> gated weights -> compacted (lambda folded) ----------
__global__ void weights_kernel(const float* __restrict__ conf) {
    __shared__ float s_w[PD];
    const int p = threadIdx.x;
    if (p < PD) {
        float s = 0.f;
#pragma unroll
        for (int b = 0; b < BD; ++b)
            s += 1.f / (1.f + expf(-g_logits[b * PD + p]));
        s *= (1.f / BD);
        s_w[p] = (s > SIM_THR) ? s * conf[p] : 0.f;
    }
    __syncthreads();
    if (threadIdx.x == 0) {
        int n = 0;
        for (int q = 0; q < PD; ++q) {
            if (s_w[q] != 0.f) { g_idx[n] = q; g_w[n] = s_w[q] * LAMBDA; ++n; }
        }
        g_nnz = n;
    }
}

// -------- K4: out[b,i,j] = attn[b,i,j] + sum_t w[t]*biases[idx[t],i,j] ------
__global__ __launch_bounds__(256) void out_kernel(const float* __restrict__ attn,
                                                  const float* __restrict__ biases,
                                                  float* __restrict__ out) {
    const int i = blockIdx.x;                  // row 0..T-1
    __shared__ float s_w[PD];
    __shared__ int   s_idx[PD];
    __shared__ int   s_n;
    if (threadIdx.x == 0) s_n = g_nnz;
    if (threadIdx.x < PD) { s_w[threadIdx.x] = g_w[threadIdx.x]; s_idx[threadIdx.x] = g_idx[threadIdx.x]; }
    __syncthreads();
    const int n = s_n;

    const size_t rowoff = (size_t)i * TD + (size_t)threadIdx.x * 4;
    float4 acc = make_float4(0.f, 0.f, 0.f, 0.f);
    for (int t = 0; t < n; ++t) {
        const float w = s_w[t];
        const float4 bv = *(const float4*)(biases + (size_t)s_idx[t] * TD * TD + rowoff);
        acc.x = fmaf(w, bv.x, acc.x);
        acc.y = fmaf(w, bv.y, acc.y);
        acc.z = fmaf(w, bv.z, acc.z);
        acc.w = fmaf(w, bv.w, acc.w);
    }
#pragma unroll
    for (int b = 0; b < BD; ++b) {
        const size_t off = (size_t)b * TD * TD + rowoff;
        const float4 av = *(const float4*)(attn + off);
        float4 ov;
        ov.x = av.x + acc.x;
        ov.y = av.y + acc.y;
        ov.z = av.z + acc.z;
        ov.w = av.w + acc.w;
        *(float4*)(out + off) = ov;
    }
}

extern "C" void kernel_launch(void* const* d_in, const int* in_sizes, int n_in,
                              void* d_out, int out_size, void* d_ws, size_t ws_size,
                              hipStream_t stream) {
    const float* attn     = (const float*)d_in[0];  // (B,T,T)
    const float* context  = (const float*)d_in[1];  // (B,C)
    const float* triggers = (const float*)d_in[2];  // (P,C)
    const float* biases   = (const float*)d_in[3];  // (P,T,T)
    const float* conf     = (const float*)d_in[4];  // (P,)
    const float* W1       = (const float*)d_in[5];  // (2C,C)
    const float* b1       = (const float*)d_in[6];  // (C,)
    const float* W2       = (const float*)d_in[7];  // (C,)
    const float* b2       = (const float*)d_in[8];  // (1,)
    float* out = (float*)d_out;

    hipLaunchKernelGGL((hidden_kernel<8, true>),  dim3(CD / 256, 1),  dim3(256), 0, stream,
                       context, triggers, W1);
    hipLaunchKernelGGL((hidden_kernel<10, false>), dim3(CD / 256, 10), dim3(256), 0, stream,
                       context, triggers, W1);
    hipLaunchKernelGGL(logits_kernel, dim3(BD * PD / 4), dim3(256), 0, stream, b1, W2, b2);
    hipLaunchKernelGGL(weights_kernel, dim3(1), dim3(128), 0, stream, conf);
    hipLaunchKernelGGL(out_kernel, dim3(TD), dim3(256), 0, stream, attn, biases, out);
}

// Round 2
// 160.752 us; speedup vs baseline: 2.3715x; 2.3715x over previous
//
#include <hip/hip_runtime.h>
#include <hip/hip_bf16.h>
#include <math.h>

#define BD 8        // batch
#define TD 1024     // T
#define CD 1024     // C
#define PD 100      // patterns
#define KS 4        // K-split for hidden GEMMs
#define LAMBDA 0.1f
#define SIM_THR 0.5f

// -------- device-global scratch (fully rewritten each call; deterministic) --
__device__ float g_pctx[KS][BD][CD];   // k-partials of context hidden
__device__ float g_ptrg[KS][PD][CD];   // k-partials of trigger hidden
__device__ float g_logits[BD * PD];    // (B, P)
__device__ int   g_nnz;
__device__ int   g_idx[PD];
__device__ float g_w[PD];              // compacted weights, lambda folded in

// -------- K1: partial hidden = X @ W1part over a 256-wide K slice ----------
// grid = (CD/256, nRowChunks, KS); ROWS=8 (ctx) or 10 (trigger chunk)
template <int ROWS, bool IS_CTX>
__global__ __launch_bounds__(256) void hidden_kernel(const float* __restrict__ context,
                                                     const float* __restrict__ triggers,
                                                     const float* __restrict__ W1) {
    const int c  = blockIdx.x * 256 + threadIdx.x;   // output column
    const int kz = blockIdx.z;
    const int k0 = kz * 256;
    const float* __restrict__ W1p = IS_CTX ? W1 : (W1 + (size_t)CD * CD);
    const float* __restrict__ src = IS_CTX ? context
                                           : (triggers + (size_t)blockIdx.y * 10 * CD);
    float* __restrict__ dst = IS_CTX ? &g_pctx[kz][0][0]
                                     : &g_ptrg[kz][blockIdx.y * 10][0];

    __shared__ float s_src[ROWS][256];
    for (int t = threadIdx.x; t < ROWS * 256; t += 256)
        s_src[t >> 8][t & 255] = src[(size_t)(t >> 8) * CD + k0 + (t & 255)];
    __syncthreads();

    float acc[ROWS];
#pragma unroll
    for (int i = 0; i < ROWS; ++i) acc[i] = 0.f;

#pragma unroll 4
    for (int kk = 0; kk < 256; ++kk) {
        const float wv = W1p[(size_t)(k0 + kk) * CD + c];
#pragma unroll
        for (int i = 0; i < ROWS; ++i)
            acc[i] = fmaf(s_src[i][kk], wv, acc[i]);
    }
#pragma unroll
    for (int i = 0; i < ROWS; ++i) dst[(size_t)i * CD + c] = acc[i];
}

// -------- K2: logits[b,p] = relu(sum_kz partials + b1) . W2 + b2 ------------
__global__ __launch_bounds__(256) void logits_kernel(const float* __restrict__ b1,
                                                     const float* __restrict__ W2,
                                                     const float* __restrict__ b2) {
    const int wave = threadIdx.x >> 6;
    const int lane = threadIdx.x & 63;
    const int idx  = blockIdx.x * 4 + wave;   // 0..799
    const int b = idx / PD;
    const int p = idx % PD;

    float sum = 0.f;
    for (int c = lane; c < CD; c += 64) {
        float h = b1[c];
#pragma unroll
        for (int kz = 0; kz < KS; ++kz)
            h += g_pctx[kz][b][c] + g_ptrg[kz][p][c];
        h = fmaxf(h, 0.f);
        sum = fmaf(h, W2[c], sum);
    }
#pragma unroll
    for (int off = 32; off > 0; off >>= 1) sum += __shfl_down(sum, off);
    if (lane == 0) g_logits[idx] = sum + b2[0];
}

// -------- K3: scores -> gated weights -> compacted (lambda folded) ----------
__global__ void weights_kernel(const float* __restrict__ conf) {
    __shared__ float s_w[PD];
    const int p = threadIdx.x;
    if (p < PD) {
        float s = 0.f;
#pragma unroll
        for (int b = 0; b < BD; ++b)
            s += 1.f / (1.f + expf(-g_logits[b * PD + p]));
        s *= (1.f / BD);
        s_w[p] = (s > SIM_THR) ? s * conf[p] : 0.f;
    }
    __syncthreads();
    if (threadIdx.x == 0) {
        int n = 0;
        for (int q = 0; q < PD; ++q) {
            if (s_w[q] != 0.f) { g_idx[n] = q; g_w[n] = s_w[q] * LAMBDA; ++n; }
        }
        g_nnz = n;
    }
}

// -------- K4: out[b,i,j] = attn[b,i,j] + sum_t w[t]*biases[idx[t],i,j] ------
__global__ __launch_bounds__(256) void out_kernel(const float* __restrict__ attn,
                                                  const float* __restrict__ biases,
                                                  float* __restrict__ out) {
    __shared__ float s_w[PD];
    __shared__ int   s_idx[PD];
    if (threadIdx.x < PD) {
        s_w[threadIdx.x]   = g_w[threadIdx.x];
        s_idx[threadIdx.x] = g_idx[threadIdx.x];
    }
    __syncthreads();
    const int n = g_nnz;

    const size_t rowoff = (size_t)blockIdx.x * TD + (size_t)threadIdx.x * 4;
    float4 acc = make_float4(0.f, 0.f, 0.f, 0.f);

    int t = 0;
    for (; t + 4 <= n; t += 4) {
        const float w0 = s_w[t + 0], w1 = s_w[t + 1], w2 = s_w[t + 2], w3 = s_w[t + 3];
        const float4 v0 = *(const float4*)(biases + (size_t)s_idx[t + 0] * TD * TD + rowoff);
        const float4 v1 = *(const float4*)(biases + (size_t)s_idx[t + 1] * TD * TD + rowoff);
        const float4 v2 = *(const float4*)(biases + (size_t)s_idx[t + 2] * TD * TD + rowoff);
        const float4 v3 = *(const float4*)(biases + (size_t)s_idx[t + 3] * TD * TD + rowoff);
        acc.x = fmaf(w0, v0.x, fmaf(w1, v1.x, fmaf(w2, v2.x, fmaf(w3, v3.x, acc.x))));
        acc.y = fmaf(w0, v0.y, fmaf(w1, v1.y, fmaf(w2, v2.y, fmaf(w3, v3.y, acc.y))));
        acc.z = fmaf(w0, v0.z, fmaf(w1, v1.z, fmaf(w2, v2.z, fmaf(w3, v3.z, acc.z))));
        acc.w = fmaf(w0, v0.w, fmaf(w1, v1.w, fmaf(w2, v2.w, fmaf(w3, v3.w, acc.w))));
    }
    for (; t < n; ++t) {
        const float w = s_w[t];
        const float4 bv = *(const float4*)(biases + (size_t)s_idx[t] * TD * TD + rowoff);
        acc.x = fmaf(w, bv.x, acc.x);
        acc.y = fmaf(w, bv.y, acc.y);
        acc.z = fmaf(w, bv.z, acc.z);
        acc.w = fmaf(w, bv.w, acc.w);
    }

    float4 av[BD];
#pragma unroll
    for (int b = 0; b < BD; ++b)
        av[b] = *(const float4*)(attn + (size_t)b * TD * TD + rowoff);
#pragma unroll
    for (int b = 0; b < BD; ++b) {
        float4 ov;
        ov.x = av[b].x + acc.x;
        ov.y = av[b].y + acc.y;
        ov.z = av[b].z + acc.z;
        ov.w = av[b].w + acc.w;
        *(float4*)(out + (size_t)b * TD * TD + rowoff) = ov;
    }
}

extern "C" void kernel_launch(void* const* d_in, const int* in_sizes, int n_in,
                              void* d_out, int out_size, void* d_ws, size_t ws_size,
                              hipStream_t stream) {
    const float* attn     = (const float*)d_in[0];  // (B,T,T)
    const float* context  = (const float*)d_in[1];  // (B,C)
    const float* triggers = (const float*)d_in[2];  // (P,C)
    const float* biases   = (const float*)d_in[3];  // (P,T,T)
    const float* conf     = (const float*)d_in[4];  // (P,)
    const float* W1       = (const float*)d_in[5];  // (2C,C)
    const float* b1       = (const float*)d_in[6];  // (C,)
    const float* W2       = (const float*)d_in[7];  // (C,)
    const float* b2       = (const float*)d_in[8];  // (1,)
    float* out = (float*)d_out;

    hipLaunchKernelGGL((hidden_kernel<8,  true>),  dim3(CD / 256, 1,  KS), dim3(256), 0, stream,
                       context, triggers, W1);
    hipLaunchKernelGGL((hidden_kernel<10, false>), dim3(CD / 256, 10, KS), dim3(256), 0, stream,
                       context, triggers, W1);
    hipLaunchKernelGGL(logits_kernel, dim3(BD * PD / 4), dim3(256), 0, stream, b1, W2, b2);
    hipLaunchKernelGGL(weights_kernel, dim3(1), dim3(128), 0, stream, conf);
    hipLaunchKernelGGL(out_kernel, dim3(TD), dim3(256), 0, stream, attn, biases, out);
}

// Round 3
// 107.870 us; speedup vs baseline: 3.5341x; 1.4902x over previous
//
#include <hip/hip_runtime.h>
#include <hip/hip_bf16.h>
#include <math.h>

#define BD 8        // batch
#define TD 1024     // T
#define CD 1024     // C
#define PD 100      // patterns
#define KS 8        // K-split for hidden GEMMs
#define KW (CD / KS)   // 128
#define LAMBDA 0.1f
#define SIM_THR 0.5f

// -------- device-global scratch (fully rewritten each call; deterministic) --
__device__ float g_pctx[KS][BD][CD];   // k-partials of context hidden
__device__ float g_ptrg[KS][PD][CD];   // k-partials of trigger hidden
__device__ float g_wd[PD];             // dense gated weights, lambda folded in

// -------- K1: partial hidden = X @ W1part over a 128-wide K slice ----------
// grid = (CD/256, 11, KS): y==0 -> context (8 rows), y=1..10 -> trigger chunk
__global__ __launch_bounds__(256) void hidden_kernel(const float* __restrict__ context,
                                                     const float* __restrict__ triggers,
                                                     const float* __restrict__ W1) {
    const int c  = blockIdx.x * 256 + threadIdx.x;   // output column
    const int kz = blockIdx.z;
    const int k0 = kz * KW;
    const bool is_ctx = (blockIdx.y == 0);
    const int  ych = blockIdx.y - 1;                 // trigger chunk 0..9
    const float* __restrict__ W1p = is_ctx ? W1 : (W1 + (size_t)CD * CD);
    const float* __restrict__ src = is_ctx ? context : (triggers + (size_t)ych * 10 * CD);
    float* __restrict__ dst = is_ctx ? &g_pctx[kz][0][0] : &g_ptrg[kz][ych * 10][0];
    const int nrows = is_ctx ? 8 : 10;

    __shared__ float s_src[10][KW];
    for (int t = threadIdx.x; t < 10 * KW; t += 256) {
        const int r = t / KW, k = t % KW;
        s_src[r][k] = src[(size_t)(r < nrows ? r : 0) * CD + k0 + k];
    }
    __syncthreads();

    float acc[10];
#pragma unroll
    for (int i = 0; i < 10; ++i) acc[i] = 0.f;

#pragma unroll 8
    for (int kk = 0; kk < KW; ++kk) {
        const float wv = W1p[(size_t)(k0 + kk) * CD + c];
#pragma unroll
        for (int i = 0; i < 10; ++i)
            acc[i] = fmaf(s_src[i][kk], wv, acc[i]);
    }
#pragma unroll
    for (int i = 0; i < 10; ++i)
        if (i < nrows) dst[(size_t)i * CD + c] = acc[i];
}

// -------- K2: per-pattern score -> gated weight (lambda folded) -------------
// grid = (PD), block 256. Wave w handles b = 2w, 2w+1.
__global__ __launch_bounds__(256) void score_kernel(const float* __restrict__ b1,
                                                    const float* __restrict__ W2,
                                                    const float* __restrict__ b2,
                                                    const float* __restrict__ conf) {
    const int p = blockIdx.x;
    __shared__ float s_h[CD];       // b1 + trg_h[p]
    __shared__ float s_logit[BD];

    for (int c = threadIdx.x; c < CD; c += 256) {
        float v = b1[c];
#pragma unroll
        for (int kz = 0; kz < KS; ++kz) v += g_ptrg[kz][p][c];
        s_h[c] = v;
    }
    __syncthreads();

    const int wave = threadIdx.x >> 6, lane = threadIdx.x & 63;
#pragma unroll
    for (int bb = 0; bb < 2; ++bb) {
        const int b = wave * 2 + bb;
        float sum = 0.f;
        for (int c = lane; c < CD; c += 64) {
            float v = s_h[c];
#pragma unroll
            for (int kz = 0; kz < KS; ++kz) v += g_pctx[kz][b][c];
            sum = fmaf(fmaxf(v, 0.f), W2[c], sum);
        }
#pragma unroll
        for (int off = 32; off > 0; off >>= 1) sum += __shfl_down(sum, off);
        if (lane == 0) s_logit[b] = sum + b2[0];
    }
    __syncthreads();
    if (threadIdx.x == 0) {
        float s = 0.f;
#pragma unroll
        for (int b = 0; b < BD; ++b) s += 1.f / (1.f + expf(-s_logit[b]));
        s *= (1.f / BD);
        g_wd[p] = (s > SIM_THR) ? s * conf[p] * LAMBDA : 0.f;
    }
}

// -------- K3: out[b,i,j] = attn[b,i,j] + sum_t w[t]*biases[idx[t],i,j] ------
// grid = (TD/2): each block covers 2 rows (2048 floats); thread owns 2 float4s.
__global__ __launch_bounds__(256) void out_kernel(const float* __restrict__ attn,
                                                  const float* __restrict__ biases,
                                                  float* __restrict__ out) {
    __shared__ float s_w[PD];
    __shared__ int   s_idx[PD];
    __shared__ int   s_n;
    if (threadIdx.x < PD) s_w[threadIdx.x] = g_wd[threadIdx.x];
    __syncthreads();
    if (threadIdx.x == 0) {
        int n = 0;
        for (int q = 0; q < PD; ++q)
            if (s_w[q] != 0.f) { s_idx[n] = q; s_w[n] = s_w[q]; ++n; }   // n <= q: in-place safe
        s_n = n;
    }
    __syncthreads();
    const int n = s_n;

    const size_t baseA = (size_t)blockIdx.x * 2048 + (size_t)threadIdx.x * 4;
    const size_t baseB = baseA + 1024;

    float4 aA = make_float4(0.f, 0.f, 0.f, 0.f);
    float4 aB = make_float4(0.f, 0.f, 0.f, 0.f);

    int t = 0;
    for (; t + 2 <= n; t += 2) {
        const float w0 = s_w[t], w1 = s_w[t + 1];
        const float* p0 = biases + (size_t)s_idx[t]     * (TD * TD);
        const float* p1 = biases + (size_t)s_idx[t + 1] * (TD * TD);
        const float4 v0A = *(const float4*)(p0 + baseA);
        const float4 v0B = *(const float4*)(p0 + baseB);
        const float4 v1A = *(const float4*)(p1 + baseA);
        const float4 v1B = *(const float4*)(p1 + baseB);
        aA.x = fmaf(w0, v0A.x, fmaf(w1, v1A.x, aA.x));
        aA.y = fmaf(w0, v0A.y, fmaf(w1, v1A.y, aA.y));
        aA.z = fmaf(w0, v0A.z, fmaf(w1, v1A.z, aA.z));
        aA.w = fmaf(w0, v0A.w, fmaf(w1, v1A.w, aA.w));
        aB.x = fmaf(w0, v0B.x, fmaf(w1, v1B.x, aB.x));
        aB.y = fmaf(w0, v0B.y, fmaf(w1, v1B.y, aB.y));
        aB.z = fmaf(w0, v0B.z, fmaf(w1, v1B.z, aB.z));
        aB.w = fmaf(w0, v0B.w, fmaf(w1, v1B.w, aB.w));
    }
    if (t < n) {
        const float w = s_w[t];
        const float* p0 = biases + (size_t)s_idx[t] * (TD * TD);
        const float4 vA = *(const float4*)(p0 + baseA);
        const float4 vB = *(const float4*)(p0 + baseB);
        aA.x = fmaf(w, vA.x, aA.x); aA.y = fmaf(w, vA.y, aA.y);
        aA.z = fmaf(w, vA.z, aA.z); aA.w = fmaf(w, vA.w, aA.w);
        aB.x = fmaf(w, vB.x, aB.x); aB.y = fmaf(w, vB.y, aB.y);
        aB.z = fmaf(w, vB.z, aB.z); aB.w = fmaf(w, vB.w, aB.w);
    }

#pragma unroll
    for (int b = 0; b < BD; ++b) {
        const size_t offA = (size_t)b * TD * TD + baseA;
        const size_t offB = (size_t)b * TD * TD + baseB;
        const float4 avA = *(const float4*)(attn + offA);
        const float4 avB = *(const float4*)(attn + offB);
        float4 oA, oB;
        oA.x = avA.x + aA.x; oA.y = avA.y + aA.y; oA.z = avA.z + aA.z; oA.w = avA.w + aA.w;
        oB.x = avB.x + aB.x; oB.y = avB.y + aB.y; oB.z = avB.z + aB.z; oB.w = avB.w + aB.w;
        *(float4*)(out + offA) = oA;
        *(float4*)(out + offB) = oB;
    }
}

extern "C" void kernel_launch(void* const* d_in, const int* in_sizes, int n_in,
                              void* d_out, int out_size, void* d_ws, size_t ws_size,
                              hipStream_t stream) {
    const float* attn     = (const float*)d_in[0];  // (B,T,T)
    const float* context  = (const float*)d_in[1];  // (B,C)
    const float* triggers = (const float*)d_in[2];  // (P,C)
    const float* biases   = (const float*)d_in[3];  // (P,T,T)
    const float* conf     = (const float*)d_in[4];  // (P,)
    const float* W1       = (const float*)d_in[5];  // (2C,C)
    const float* b1       = (const float*)d_in[6];  // (C,)
    const float* W2       = (const float*)d_in[7];  // (C,)
    const float* b2       = (const float*)d_in[8];  // (1,)
    float* out = (float*)d_out;

    hipLaunchKernelGGL(hidden_kernel, dim3(CD / 256, 11, KS), dim3(256), 0, stream,
                       context, triggers, W1);
    hipLaunchKernelGGL(score_kernel, dim3(PD), dim3(256), 0, stream, b1, W2, b2, conf);
    hipLaunchKernelGGL(out_kernel, dim3(TD / 2), dim3(256), 0, stream, attn, biases, out);
}

// Round 5
// 105.621 us; speedup vs baseline: 3.6093x; 1.0213x over previous
//
#include <hip/hip_runtime.h>
#include <hip/hip_bf16.h>
#include <math.h>

#define BD 8        // batch
#define TD 1024     // T
#define CD 1024     // C
#define PD 100      // patterns
#define KS 16       // K-split for hidden GEMMs
#define KW (CD / KS)   // 64
#define LAMBDA 0.1f
#define SIM_THR 0.5f

typedef float f4 __attribute__((ext_vector_type(4)));   // nontemporal-compatible float4

// -------- device-global scratch (fully rewritten each call; deterministic) --
__device__ float g_pctx[KS][BD][CD];   // k-partials of context hidden
__device__ float g_ptrg[KS][PD][CD];   // k-partials of trigger hidden
__device__ float g_wd[PD];             // dense gated weights, lambda folded in

// -------- K1: partial hidden = X @ W1part over a 64-wide K slice -----------
// grid = (CD/256, 11, KS): y==0 -> context (8 rows), y=1..10 -> trigger chunk
__global__ __launch_bounds__(256) void hidden_kernel(const float* __restrict__ context,
                                                     const float* __restrict__ triggers,
                                                     const float* __restrict__ W1) {
    const int c  = blockIdx.x * 256 + threadIdx.x;   // output column
    const int kz = blockIdx.z;
    const int k0 = kz * KW;
    const bool is_ctx = (blockIdx.y == 0);
    const int  ych = blockIdx.y - 1;                 // trigger chunk 0..9
    const float* __restrict__ W1p = is_ctx ? W1 : (W1 + (size_t)CD * CD);
    const float* __restrict__ src = is_ctx ? context : (triggers + (size_t)ych * 10 * CD);
    float* __restrict__ dst = is_ctx ? &g_pctx[kz][0][0] : &g_ptrg[kz][ych * 10][0];
    const int nrows = is_ctx ? 8 : 10;

    __shared__ float s_src[10][KW];
    for (int t = threadIdx.x; t < 10 * KW; t += 256) {
        const int r = t >> 6, k = t & (KW - 1);
        s_src[r][k] = src[(size_t)(r < nrows ? r : 0) * CD + k0 + k];
    }
    __syncthreads();

    float acc[10];
#pragma unroll
    for (int i = 0; i < 10; ++i) acc[i] = 0.f;

#pragma unroll 8
    for (int kk = 0; kk < KW; ++kk) {
        const float wv = W1p[(size_t)(k0 + kk) * CD + c];
#pragma unroll
        for (int i = 0; i < 10; ++i)
            acc[i] = fmaf(s_src[i][kk], wv, acc[i]);
    }
#pragma unroll
    for (int i = 0; i < 10; ++i)
        if (i < nrows) dst[(size_t)i * CD + c] = acc[i];
}

// -------- K2: per-pattern score -> gated weight (lambda folded) -------------
// grid = (PD), block 512: wave w handles batch row b=w.
__global__ __launch_bounds__(512) void score_kernel(const float* __restrict__ b1,
                                                    const float* __restrict__ W2,
                                                    const float* __restrict__ b2,
                                                    const float* __restrict__ conf) {
    const int p = blockIdx.x;
    __shared__ float s_h[CD];       // b1 + trg_h[p]
    __shared__ float s_logit[BD];

    for (int c = threadIdx.x; c < CD; c += 512) {
        float v = b1[c];
#pragma unroll
        for (int kz = 0; kz < KS; ++kz) v += g_ptrg[kz][p][c];
        s_h[c] = v;
    }
    __syncthreads();

    const int b = threadIdx.x >> 6, lane = threadIdx.x & 63;
    float sum = 0.f;
    for (int c = lane; c < CD; c += 64) {
        float v = s_h[c];
#pragma unroll
        for (int kz = 0; kz < KS; ++kz) v += g_pctx[kz][b][c];
        sum = fmaf(fmaxf(v, 0.f), W2[c], sum);
    }
#pragma unroll
    for (int off = 32; off > 0; off >>= 1) sum += __shfl_down(sum, off);
    if (lane == 0) s_logit[b] = sum + b2[0];
    __syncthreads();
    if (threadIdx.x == 0) {
        float s = 0.f;
#pragma unroll
        for (int bb = 0; bb < BD; ++bb) s += 1.f / (1.f + expf(-s_logit[bb]));
        s *= (1.f / BD);
        g_wd[p] = (s > SIM_THR) ? s * conf[p] * LAMBDA : 0.f;
    }
}

// -------- K3: out[b,i,j] = attn[b,i,j] + sum_t w[t]*biases[idx[t],i,j] ------
// grid = (TD): one row per block; thread owns 1 float4; pattern loop unroll x8.
__global__ __launch_bounds__(256) void out_kernel(const float* __restrict__ attn,
                                                  const float* __restrict__ biases,
                                                  float* __restrict__ out) {
    __shared__ float s_w[PD];
    __shared__ unsigned long long s_off[PD];   // compacted plane element-offsets
    __shared__ int s_n;
    if (threadIdx.x < PD) s_w[threadIdx.x] = g_wd[threadIdx.x];
    __syncthreads();
    if (threadIdx.x == 0) {
        int n = 0;
        for (int q = 0; q < PD; ++q)
            if (s_w[q] != 0.f) {
                s_w[n] = s_w[q];                                  // n <= q: in-place safe
                s_off[n] = (unsigned long long)q * (TD * TD);
                ++n;
            }
        s_n = n;
    }
    __syncthreads();
    const int n = s_n;

    const size_t rowoff = (size_t)blockIdx.x * TD + (size_t)threadIdx.x * 4;
    f4 acc = {0.f, 0.f, 0.f, 0.f};

    int t = 0;
    for (; t + 8 <= n; t += 8) {
        float w[8];
        const f4* p[8];
#pragma unroll
        for (int u = 0; u < 8; ++u) {
            w[u] = s_w[t + u];
            p[u] = (const f4*)(biases + (size_t)s_off[t + u] + rowoff);
        }
        f4 v[8];
#pragma unroll
        for (int u = 0; u < 8; ++u) v[u] = __builtin_nontemporal_load(p[u]);
#pragma unroll
        for (int u = 0; u < 8; ++u) {
            acc.x = fmaf(w[u], v[u].x, acc.x);
            acc.y = fmaf(w[u], v[u].y, acc.y);
            acc.z = fmaf(w[u], v[u].z, acc.z);
            acc.w = fmaf(w[u], v[u].w, acc.w);
        }
    }
    for (; t < n; ++t) {
        const float w = s_w[t];
        const f4 bv = __builtin_nontemporal_load(
            (const f4*)(biases + (size_t)s_off[t] + rowoff));
        acc.x = fmaf(w, bv.x, acc.x);
        acc.y = fmaf(w, bv.y, acc.y);
        acc.z = fmaf(w, bv.z, acc.z);
        acc.w = fmaf(w, bv.w, acc.w);
    }

    f4 av[BD];
#pragma unroll
    for (int b = 0; b < BD; ++b)
        av[b] = __builtin_nontemporal_load((const f4*)(attn + (size_t)b * TD * TD + rowoff));
#pragma unroll
    for (int b = 0; b < BD; ++b) {
        f4 ov = av[b] + acc;
        __builtin_nontemporal_store(ov, (f4*)(out + (size_t)b * TD * TD + rowoff));
    }
}

extern "C" void kernel_launch(void* const* d_in, const int* in_sizes, int n_in,
                              void* d_out, int out_size, void* d_ws, size_t ws_size,
                              hipStream_t stream) {
    const float* attn     = (const float*)d_in[0];  // (B,T,T)
    const float* context  = (const float*)d_in[1];  // (B,C)
    const float* triggers = (const float*)d_in[2];  // (P,C)
    const float* biases   = (const float*)d_in[3];  // (P,T,T)
    const float* conf     = (const float*)d_in[4];  // (P,)
    const float* W1       = (const float*)d_in[5];  // (2C,C)
    const float* b1       = (const float*)d_in[6];  // (C,)
    const float* W2       = (const float*)d_in[7];  // (C,)
    const float* b2       = (const float*)d_in[8];  // (1,)
    float* out = (float*)d_out;

    hipLaunchKernelGGL(hidden_kernel, dim3(CD / 256, 11, KS), dim3(256), 0, stream,
                       context, triggers, W1);
    hipLaunchKernelGGL(score_kernel, dim3(PD), dim3(512), 0, stream, b1, W2, b2, conf);
    hipLaunchKernelGGL(out_kernel, dim3(TD), dim3(256), 0, stream, attn, biases, out);
}